// Round 8
// baseline (136.996 us; speedup 1.0000x reference)
//
#include <hip/hip_runtime.h>
#include <cstdint>
#include <cstddef>

// ---------------- problem constants ----------------
#define Bn   16
#define Cn   256
#define Nn   4096      // 16^3 spatial
#define Ln   77
#define LPn  80        // padded L rows (scores), 5 tiles of 16
#define LKn  96        // padded L for PV K-dim (3 k-steps of 32)
#define CTXn 768
#define Gn   32

typedef unsigned short u16;
typedef unsigned int   u32;
using frag8 = __attribute__((ext_vector_type(8))) short;   // 8 x bf16 (4 VGPR)
using f32x4 = __attribute__((ext_vector_type(4))) float;
using u16x4 = __attribute__((ext_vector_type(4))) u16;
using u16x8 = __attribute__((ext_vector_type(8))) u16;

__device__ __forceinline__ float b2f(u16 b) {
    union { u32 u; float f; } v; v.u = ((u32)b) << 16; return v.f;
}
__device__ __forceinline__ u16 f2b(float f) {  // RNE f32->bf16
    union { float f; u32 u; } v; v.f = f;
    u32 u = v.u;
    return (u16)((u + 0x7fffu + ((u >> 16) & 1u)) >> 16);
}
__device__ __forceinline__ u16x4 cast4(f32x4 s) {
    u16x4 p; p[0] = f2b(s[0]); p[1] = f2b(s[1]); p[2] = f2b(s[2]); p[3] = f2b(s[3]);
    return p;
}
// async global->LDS, 16B per lane. LDS dest must be lane-linear (base + lane*16).
__device__ __forceinline__ void gl16(const u16* g, u16* l) {
    __builtin_amdgcn_global_load_lds((const __attribute__((address_space(1))) u32*)g,
                                     (__attribute__((address_space(3))) u32*)l, 16, 0, 0);
}

// Chunked activation layout (per 64n tile): [kc(32)][row(64)] of 16B chunks (8 ch).
//   u16 index = (kc*64 + row)*8 + (c&7),  kc = c>>3, row = n&63.
// Chunked weight layout: [kc(32)][row(256)]: u16 idx = ((k>>3)*256 + r)*8 + (k&7).
// Chunked kt layout:     [b][kc(32)][l(80)]: u16 idx = b*20480 + ((c>>3)*80 + l)*8 + (c&7).

// ---------------- ws layout (bytes) ----------------
static const size_t OFF_T   = 33554432;             // bf16 chunked t [B][64][2048][8]
static const size_t OFF_CTXB = 33554432 - 2097152;  // bf16 [16][80][768] (dead before fused; t region starts after)
static const size_t OFF_KWB  = 35520512;            // bf16 [256][768]   (unused region vs t? see note)
static const size_t OFF_VWB  = 35913728;            // bf16 [256][768]
static const size_t OFF_KT  = 67108864;             // bf16 chunked [B][32][80][8] (40KB/b)
static const size_t OFF_V   = 67764224;             // bf16 [B][256][96]
static const size_t OFF_QWB = 68550656;             // bf16 chunked [32][256][8]
static const size_t OFF_OWB = 68681728;             // bf16 chunked [32][256][8]
static const size_t OFF_GS  = 68812800;             // f32 [B][32]
static const size_t OFF_GQ  = 68814848;             // f32 [B][32]
// NOTE: ctxb/kwb/vwb live in [31.4M, 36.3M). kwb/vwb overlap t's region [33.5M,67.1M)
// but are dead after k_kv which runs BEFORE k_fused writes t (stream-serialized). ctxb
// sits below OFF_T so nothing overlaps it while alive.

// ---------------- 1: cast to bf16 (qw/ow chunked) + zero GN accumulators ----------------
__global__ void k_prep(const float* __restrict__ qw, const float* __restrict__ ow,
                       const float* __restrict__ kw, const float* __restrict__ vw,
                       const float* __restrict__ ctx,
                       u16* __restrict__ qwb, u16* __restrict__ owb,
                       u16* __restrict__ kwb, u16* __restrict__ vwb,
                       u16* __restrict__ ctxb, float* __restrict__ gz) {
    int i = blockIdx.x * 256 + threadIdx.x;        // 376832 total
    if (i < 1024) gz[i] = 0.f;                     // gsum+gsq (4KB, contiguous)
    if (i < 16384) {
        int e = i * 4; int r = e >> 8; int k = e & 255;
        *(u16x4*)(qwb + ((size_t)((k >> 3) * 256 + r) * 8 + (k & 7))) =
            cast4(*(const f32x4*)(qw + e));
    } else if (i < 32768) {
        int e = (i - 16384) * 4; int r = e >> 8; int k = e & 255;
        *(u16x4*)(owb + ((size_t)((k >> 3) * 256 + r) * 8 + (k & 7))) =
            cast4(*(const f32x4*)(ow + e));
    } else if (i < 81920) {
        int j = i - 32768;
        *(u16x4*)(kwb + j * 4) = cast4(*(const f32x4*)(kw + j * 4));
    } else if (i < 131072) {
        int j = i - 81920;
        *(u16x4*)(vwb + j * 4) = cast4(*(const f32x4*)(vw + j * 4));
    } else {
        int j = i - 131072;                        // 0..245759
        int e = j * 4;
        int row = e / CTXn;                        // b*80 + l
        int d = e - row * CTXn;
        int b = row / LPn, l = row - b * LPn;
        u16x4 pk;
        if (l < Ln) {
            pk = cast4(*(const f32x4*)(ctx + ((size_t)(b * Ln + l)) * CTXn + d));
        } else {
            pk[0] = 0; pk[1] = 0; pk[2] = 0; pk[3] = 0;
        }
        *(u16x4*)(ctxb + e) = pk;
    }
}

// ---------------- 2: k/v projections via MFMA (kt stored chunked) ----------------
__launch_bounds__(256)
__global__ void k_kv(const u16* __restrict__ kwb, const u16* __restrict__ vwb,
                     const u16* __restrict__ ctxb, u16* __restrict__ kt,
                     u16* __restrict__ v) {
    int b = blockIdx.y;
    int tid = threadIdx.x;
    int wave = tid >> 6, lane = tid & 63;
    int l15 = lane & 15, q4 = lane >> 4;
    int c0 = blockIdx.x * 64 + wave * 16;
    const u16* cb = ctxb + (size_t)b * LPn * CTXn;

    f32x4 ak[5], av[5];
#pragma unroll
    for (int lt = 0; lt < 5; ++lt) {
        ak[lt] = (f32x4){0.f, 0.f, 0.f, 0.f};
        av[lt] = (f32x4){0.f, 0.f, 0.f, 0.f};
    }
    for (int ks = 0; ks < CTXn / 32; ++ks) {
        int kk = ks * 32 + 8 * q4;
        frag8 fk = *(const frag8*)(kwb + (size_t)(c0 + l15) * CTXn + kk);
        frag8 fv = *(const frag8*)(vwb + (size_t)(c0 + l15) * CTXn + kk);
#pragma unroll
        for (int lt = 0; lt < 5; ++lt) {
            frag8 fc = *(const frag8*)(cb + (size_t)(lt * 16 + l15) * CTXn + kk);
            ak[lt] = __builtin_amdgcn_mfma_f32_16x16x32_bf16(fk, fc, ak[lt], 0, 0, 0);
            av[lt] = __builtin_amdgcn_mfma_f32_16x16x32_bf16(fc, fv, av[lt], 0, 0, 0);
        }
    }
    // kt chunked: D row = c (q4*4..+3), col = l (l15)
    int cc0 = c0 + q4 * 4;
    u16* ktb = kt + (size_t)b * 20480;
#pragma unroll
    for (int lt = 0; lt < 5; ++lt) {
        *(u16x4*)(ktb + (size_t)((cc0 >> 3) * LPn + lt * 16 + l15) * 8 + (cc0 & 7)) = cast4(ak[lt]);
        // v: D row = l (q4*4..+3), col = c (l15)
        *(u16x4*)(v + ((size_t)(b * Cn + c0 + l15)) * LKn + lt * 16 + q4 * 4) = cast4(av[lt]);
    }
    u16x4 z; z[0] = 0; z[1] = 0; z[2] = 0; z[3] = 0;
    *(u16x4*)(v + ((size_t)(b * Cn + c0 + l15)) * LKn + 80 + q4 * 4) = z;
}

// ---------------- 3: FUSED q-proj -> QK^T -> softmax -> PV -> out-proj + GN ----------------
// One 64n tile per block. 4 waves. LDS: sX (x bf16, 32KB) + sQH (q then h, 32KB) +
// wl (softmax w, 13KB) = 77KB -> 2 blocks/CU. Weights/kt/v read from global (L2-hot).
__launch_bounds__(256, 2)
__global__ void k_fused(const u16* __restrict__ qwb, const u16* __restrict__ owb,
                        const float* __restrict__ x, const float* __restrict__ qb,
                        const float* __restrict__ obias,
                        const u16* __restrict__ ktg, const u16* __restrict__ vg,
                        u16* __restrict__ t, float* __restrict__ gsum,
                        float* __restrict__ gsq) {
    int nt = blockIdx.x, b = blockIdx.y;
    int tid = threadIdx.x;
    int w = tid >> 6, lane = tid & 63;
    int l15 = lane & 15, q4 = lane >> 4;

    __shared__ __align__(16) u16 sX[16384];     // x tile, bf16 chunked (residual too)
    __shared__ __align__(16) u16 sQH[16384];    // q tile, then h tile
    __shared__ u16 wl[4][16][104];              // per-wave softmax weights

    // ---- phase 0: stage x (64n x 256c f32) -> sX bf16 chunked ----
    {
        const float* xb = x + (size_t)b * Cn * Nn + nt * 64;
        int cs = tid >> 4;                      // 0..15
        int ns = (tid & 15) * 4;
#pragma unroll
        for (int p = 0; p < 16; ++p) {
            int c = p * 16 + cs;
            f32x4 v4 = *(const f32x4*)(xb + (size_t)c * Nn + ns);
            u16* dst = &sX[(size_t)((c >> 3) * 64) * 8 + (c & 7)];
#pragma unroll
            for (int j = 0; j < 4; ++j) dst[(ns + j) * 8] = f2b(v4[j]);
        }
    }
    __syncthreads();

    // ---- phase A: q-GEMM (wave w owns o in [w*64, w*64+64)) ----
    {
        f32x4 acc[4][4];
#pragma unroll
        for (int i = 0; i < 4; ++i)
#pragma unroll
            for (int j = 0; j < 4; ++j) acc[i][j] = (f32x4){0.f, 0.f, 0.f, 0.f};
#pragma unroll
        for (int ks = 0; ks < 8; ++ks) {
            frag8 bf[4];
#pragma unroll
            for (int n4 = 0; n4 < 4; ++n4)
                bf[n4] = *(const frag8*)&sX[(size_t)((ks * 4 + q4) * 64 + n4 * 16 + l15) * 8];
#pragma unroll
            for (int mt = 0; mt < 4; ++mt) {
                frag8 a = *(const frag8*)(qwb + (size_t)((ks * 4 + q4) * 256 + w * 64 + mt * 16 + l15) * 8);
#pragma unroll
                for (int n4 = 0; n4 < 4; ++n4)
                    acc[mt][n4] = __builtin_amdgcn_mfma_f32_16x16x32_bf16(a, bf[n4], acc[mt][n4], 0, 0, 0);
            }
        }
        // D row = o (q4*4+r), col = n (l15): + bias, write sQH chunked
#pragma unroll
        for (int mt = 0; mt < 4; ++mt) {
            int o4 = w * 64 + mt * 16 + q4 * 4;
            f32x4 qb4 = *(const f32x4*)(qb + o4);
#pragma unroll
            for (int n4 = 0; n4 < 4; ++n4) {
                int row = n4 * 16 + l15;
                u16x4 pk;
#pragma unroll
                for (int r = 0; r < 4; ++r) pk[r] = f2b(acc[mt][n4][r] + qb4[r]);
                *(u16x4*)&sQH[(size_t)((o4 >> 3) * 64 + row) * 8 + (o4 & 7)] = pk;
            }
        }
    }
    __syncthreads();

    // ---- phase B: QK^T (wave w owns n-rows [w*16, w*16+16)) + softmax ----
    int rw = w * 16;
    const u16* ktb = ktg + (size_t)b * 20480;
    f32x4 s5[5];
#pragma unroll
    for (int mt = 0; mt < 5; ++mt) s5[mt] = (f32x4){0.f, 0.f, 0.f, 0.f};
#pragma unroll
    for (int ks = 0; ks < 8; ++ks) {
        frag8 bq = *(const frag8*)&sQH[(size_t)((ks * 4 + q4) * 64 + rw + l15) * 8];
#pragma unroll
        for (int mt = 0; mt < 5; ++mt) {
            frag8 ak = *(const frag8*)(ktb + (size_t)((ks * 4 + q4) * 80 + mt * 16 + l15) * 8);
            s5[mt] = __builtin_amdgcn_mfma_f32_16x16x32_bf16(ak, bq, s5[mt], 0, 0, 0);
        }
    }
    // lane: n = l15, l = mt*16 + q4*4 + r
    {
        float m = -3e38f;
#pragma unroll
        for (int mt = 0; mt < 5; ++mt)
#pragma unroll
            for (int r = 0; r < 4; ++r) {
                int l = mt * 16 + q4 * 4 + r;
                if (l < Ln) m = fmaxf(m, s5[mt][r]);
            }
        m = fmaxf(m, __shfl_xor(m, 16));
        m = fmaxf(m, __shfl_xor(m, 32));
        float p[5][4];
        float sum = 0.f;
#pragma unroll
        for (int mt = 0; mt < 5; ++mt)
#pragma unroll
            for (int r = 0; r < 4; ++r) {
                int l = mt * 16 + q4 * 4 + r;
                float e = (l < Ln) ? __expf(s5[mt][r] - m) : 0.f;
                p[mt][r] = e;
                sum += e;
            }
        sum += __shfl_xor(sum, 16);
        sum += __shfl_xor(sum, 32);
        float inv = 1.f / sum;

        u32* wz = (u32*)&wl[w][0][0];           // 832 u32, per-wave region
#pragma unroll
        for (int i = 0; i < 13; ++i) wz[lane + i * 64] = 0;
#pragma unroll
        for (int mt = 0; mt < 5; ++mt)
#pragma unroll
            for (int r = 0; r < 4; ++r) {
                int l = mt * 16 + q4 * 4 + r;
                if (l < Ln) wl[w][l15][l] = f2b(p[mt][r] * inv);
            }
    }
    __syncthreads();    // all sQH(q) reads done -> safe to overwrite with h

    // ---- phase C: PV (h[n][c] -> sQH chunked, rows rw..rw+16) ----
    {
        frag8 aw[3];
#pragma unroll
        for (int ks = 0; ks < 3; ++ks)
            aw[ks] = *(const frag8*)(&wl[w][l15][ks * 32 + 8 * q4]);
        const u16* vb = vg + (size_t)b * Cn * LKn;
#pragma unroll
        for (int ct = 0; ct < 16; ++ct) {
            f32x4 h = (f32x4){0.f, 0.f, 0.f, 0.f};
#pragma unroll
            for (int ks = 0; ks < 3; ++ks) {
                frag8 bv = *(const frag8*)(vb + (size_t)(ct * 16 + l15) * LKn + ks * 32 + 8 * q4);
                h = __builtin_amdgcn_mfma_f32_16x16x32_bf16(aw[ks], bv, h, 0, 0, 0);
            }
            int kc = ct * 2 + (l15 >> 3), off = l15 & 7;
#pragma unroll
            for (int r = 0; r < 4; ++r)
                sQH[(size_t)(kc * 64 + rw + q4 * 4 + r) * 8 + off] = f2b(h[r]);
        }
    }
    __syncthreads();

    // ---- phase D: out-GEMM + bias + residual(sX) + chunked t store + GN partials ----
    {
        f32x4 acc[4][4];
#pragma unroll
        for (int i = 0; i < 4; ++i)
#pragma unroll
            for (int j = 0; j < 4; ++j) acc[i][j] = (f32x4){0.f, 0.f, 0.f, 0.f};
#pragma unroll
        for (int ks = 0; ks < 8; ++ks) {
            frag8 bf[4];
#pragma unroll
            for (int n4 = 0; n4 < 4; ++n4)
                bf[n4] = *(const frag8*)&sQH[(size_t)((ks * 4 + q4) * 64 + n4 * 16 + l15) * 8];
#pragma unroll
            for (int mt = 0; mt < 4; ++mt) {
                frag8 a = *(const frag8*)(owb + (size_t)((ks * 4 + q4) * 256 + w * 64 + mt * 16 + l15) * 8);
#pragma unroll
                for (int n4 = 0; n4 < 4; ++n4)
                    acc[mt][n4] = __builtin_amdgcn_mfma_f32_16x16x32_bf16(a, bf[n4], acc[mt][n4], 0, 0, 0);
            }
        }
        u16* tb = t + ((size_t)(b * 64 + nt)) * 16384;
        float gps[4] = {0.f, 0.f, 0.f, 0.f}, gpq[4] = {0.f, 0.f, 0.f, 0.f};
#pragma unroll
        for (int mt = 0; mt < 4; ++mt) {
            int o4 = w * 64 + mt * 16 + q4 * 4;
            f32x4 ob4 = *(const f32x4*)(obias + o4);
            size_t kcb = (size_t)(o4 >> 3) * 64;
            int off = o4 & 7;
#pragma unroll
            for (int n4 = 0; n4 < 4; ++n4) {
                int row = n4 * 16 + l15;
                size_t idx = (kcb + row) * 8 + off;
                u16x4 xv = *(const u16x4*)&sX[idx];
                u16x4 pk;
#pragma unroll
                for (int r = 0; r < 4; ++r) {
                    float val = acc[mt][n4][r] + ob4[r] + b2f(xv[r]);
                    pk[r] = f2b(val);
                    gps[mt] += val; gpq[mt] += val * val;
                }
                *(u16x4*)(tb + idx) = pk;
            }
        }
        // GN reduce: lane's 4 vals in group g = w*8 + mt*2 + (q4>>1)
#pragma unroll
        for (int mt = 0; mt < 4; ++mt) {
            float s = gps[mt], q = gpq[mt];
            s += __shfl_xor(s, 1);  q += __shfl_xor(q, 1);
            s += __shfl_xor(s, 2);  q += __shfl_xor(q, 2);
            s += __shfl_xor(s, 4);  q += __shfl_xor(q, 4);
            s += __shfl_xor(s, 8);  q += __shfl_xor(q, 8);
            s += __shfl_xor(s, 16); q += __shfl_xor(q, 16);
            if ((lane & 31) == 0) {   // lane 0 (q4 0/1) or lane 32 (q4 2/3)
                int g = w * 8 + mt * 2 + (lane >> 5);
                atomicAdd(&gsum[b * Gn + g], s);
                atomicAdd(&gsq[b * Gn + g], q);
            }
        }
    }
}

// ---------------- 4: GroupNorm apply + Swish (chunked t -> [b][c][n] f32 out) ----------------
__launch_bounds__(256)
__global__ void k_gnapply(const u16* __restrict__ t, const float* __restrict__ gsum,
                          const float* __restrict__ gsq, const float* __restrict__ gamma,
                          const float* __restrict__ beta, float* __restrict__ out) {
    int nt = blockIdx.x, b = blockIdx.y;
    __shared__ __align__(16) u16 s[16384];          // 32KB tile
    const u16* tb = t + ((size_t)(b * 64 + nt)) * 16384;
    int tid = threadIdx.x;
#pragma unroll
    for (int j = 0; j < 8; ++j) {
        int c = j * 256 + tid;
        gl16(tb + (size_t)c * 8, &s[(size_t)c * 8]);
    }
    int c8 = tid >> 3, n8 = tid & 7;                // group g = c8, n-base = n8*8
    float mean = gsum[b * Gn + c8] * (1.0f / 32768.f);
    float var = gsq[b * Gn + c8] * (1.0f / 32768.f) - mean * mean;
    float rstd = rsqrtf(var + 1e-5f);
    __syncthreads();
    u16x8 v[8];
#pragma unroll
    for (int j = 0; j < 8; ++j)
        v[j] = *(const u16x8*)&s[(size_t)(c8 * 64 + n8 * 8 + j) * 8];
    float* ob = out + ((size_t)(b * Cn + c8 * 8)) * Nn + nt * 64 + n8 * 8;
#pragma unroll
    for (int cc = 0; cc < 8; ++cc) {
        float ga = gamma[c8 * 8 + cc], be = beta[c8 * 8 + cc];
        f32x4 lo, hi;
#pragma unroll
        for (int j = 0; j < 4; ++j) {
            float hv = (b2f(v[j][cc]) - mean) * rstd * ga + be;
            lo[j] = hv / (1.f + __expf(-hv));
        }
#pragma unroll
        for (int j = 0; j < 4; ++j) {
            float hv = (b2f(v[j + 4][cc]) - mean) * rstd * ga + be;
            hi[j] = hv / (1.f + __expf(-hv));
        }
        *(f32x4*)(ob + (size_t)cc * Nn) = lo;
        *(f32x4*)(ob + (size_t)cc * Nn + 4) = hi;
    }
}

// ---------------- launcher ----------------
extern "C" void kernel_launch(void* const* d_in, const int* in_sizes, int n_in,
                              void* d_out, int out_size, void* d_ws, size_t ws_size,
                              hipStream_t stream) {
    (void)in_sizes; (void)n_in; (void)out_size; (void)ws_size;
    const float* x     = (const float*)d_in[0];
    const float* ctx   = (const float*)d_in[1];
    const float* qw    = (const float*)d_in[2];
    const float* qb    = (const float*)d_in[3];
    const float* kw    = (const float*)d_in[4];
    const float* vw    = (const float*)d_in[5];
    const float* ow    = (const float*)d_in[6];
    const float* ob    = (const float*)d_in[7];
    const float* gamma = (const float*)d_in[8];
    const float* beta  = (const float*)d_in[9];
    float* out = (float*)d_out;
    char* ws = (char*)d_ws;

    u16* t    = (u16*)(ws + OFF_T);
    u16* ctxb = (u16*)(ws + OFF_CTXB);
    u16* kwb  = (u16*)(ws + OFF_KWB);
    u16* vwb  = (u16*)(ws + OFF_VWB);
    u16* kt   = (u16*)(ws + OFF_KT);
    u16* v    = (u16*)(ws + OFF_V);
    u16* qwb  = (u16*)(ws + OFF_QWB);
    u16* owb  = (u16*)(ws + OFF_OWB);
    float* gsum = (float*)(ws + OFF_GS);
    float* gsq  = (float*)(ws + OFF_GQ);

    k_prep<<<1472, 256, 0, stream>>>(qw, ow, kw, vw, ctx, qwb, owb, kwb, vwb, ctxb, gsum);
    k_kv<<<dim3(4, Bn), 256, 0, stream>>>(kwb, vwb, ctxb, kt, v);
    k_fused<<<dim3(64, Bn), 256, 0, stream>>>(qwb, owb, x, qb, ob, kt, v, t, gsum, gsq);
    k_gnapply<<<dim3(64, Bn), 256, 0, stream>>>(t, gsum, gsq, gamma, beta, out);
}

// Round 9
// 135.881 us; speedup vs baseline: 1.0082x; 1.0082x over previous
//
#include <hip/hip_runtime.h>
#include <cstdint>
#include <cstddef>

// ---------------- problem constants ----------------
#define Bn   16
#define Cn   256
#define Nn   4096      // 16^3 spatial
#define Ln   77
#define LPn  80        // padded L rows (scores), 5 tiles of 16
#define LKn  96        // padded L for PV K-dim (3 k-steps of 32)
#define CTXn 768
#define Gn   32

typedef unsigned short u16;
typedef unsigned int   u32;
using frag8 = __attribute__((ext_vector_type(8))) short;   // 8 x bf16 (4 VGPR)
using f32x4 = __attribute__((ext_vector_type(4))) float;
using u16x4 = __attribute__((ext_vector_type(4))) u16;
using u16x8 = __attribute__((ext_vector_type(8))) u16;

__device__ __forceinline__ float b2f(u16 b) {
    union { u32 u; float f; } v; v.u = ((u32)b) << 16; return v.f;
}
__device__ __forceinline__ u16 f2b(float f) {  // RNE f32->bf16
    union { float f; u32 u; } v; v.f = f;
    u32 u = v.u;
    return (u16)((u + 0x7fffu + ((u >> 16) & 1u)) >> 16);
}
__device__ __forceinline__ u16x4 cast4(f32x4 s) {
    u16x4 p; p[0] = f2b(s[0]); p[1] = f2b(s[1]); p[2] = f2b(s[2]); p[3] = f2b(s[3]);
    return p;
}
// async global->LDS, 16B per lane. LDS dest must be lane-linear (base + lane*16).
__device__ __forceinline__ void gl16(const u16* g, u16* l) {
    __builtin_amdgcn_global_load_lds((const __attribute__((address_space(1))) u32*)g,
                                     (__attribute__((address_space(3))) u32*)l, 16, 0, 0);
}

// Chunked activation layout (per 64n tile): [kc(32)][row(64)] of 16B chunks (8 ch).
//   u16 index = (kc*64 + row)*8 + (c&7),  kc = c>>3, row = n&63.
// Chunked weight layout: [kc(32)][row(256)]: u16 idx = ((k>>3)*256 + r)*8 + (k&7).
// Chunked kt layout:     [b][kc(32)][l(80)]: u16 idx = b*20480 + ((c>>3)*80 + l)*8 + (c&7).

// ---------------- ws layout (bytes) ----------------
static const size_t OFF_T   = 33554432;             // bf16 chunked t [B][64][2048][8]
static const size_t OFF_CTXB = 33554432 - 2097152;  // bf16 [16][80][768] (dead before fused)
static const size_t OFF_KWB  = 35520512;            // bf16 [256][768] (dead after k_kv)
static const size_t OFF_VWB  = 35913728;            // bf16 [256][768] (dead after k_kv)
static const size_t OFF_KT  = 67108864;             // bf16 chunked [B][32][80][8] (40KB/b)
static const size_t OFF_V   = 67764224;             // bf16 [B][256][96]
static const size_t OFF_QWB = 68550656;             // bf16 chunked [32][256][8]
static const size_t OFF_OWB = 68681728;             // bf16 chunked [32][256][8]
static const size_t OFF_GS  = 68812800;             // f32 [B][32]
static const size_t OFF_GQ  = 68814848;             // f32 [B][32]
// kwb/vwb overlap t's region but die before k_fused writes t (stream-serialized).

// ---------------- 1: cast to bf16 (qw/ow chunked) + zero GN accumulators ----------------
__global__ void k_prep(const float* __restrict__ qw, const float* __restrict__ ow,
                       const float* __restrict__ kw, const float* __restrict__ vw,
                       const float* __restrict__ ctx,
                       u16* __restrict__ qwb, u16* __restrict__ owb,
                       u16* __restrict__ kwb, u16* __restrict__ vwb,
                       u16* __restrict__ ctxb, float* __restrict__ gz) {
    int i = blockIdx.x * 256 + threadIdx.x;        // 376832 total
    if (i < 1024) gz[i] = 0.f;                     // gsum+gsq (4KB, contiguous)
    if (i < 16384) {
        int e = i * 4; int r = e >> 8; int k = e & 255;
        *(u16x4*)(qwb + ((size_t)((k >> 3) * 256 + r) * 8 + (k & 7))) =
            cast4(*(const f32x4*)(qw + e));
    } else if (i < 32768) {
        int e = (i - 16384) * 4; int r = e >> 8; int k = e & 255;
        *(u16x4*)(owb + ((size_t)((k >> 3) * 256 + r) * 8 + (k & 7))) =
            cast4(*(const f32x4*)(ow + e));
    } else if (i < 81920) {
        int j = i - 32768;
        *(u16x4*)(kwb + j * 4) = cast4(*(const f32x4*)(kw + j * 4));
    } else if (i < 131072) {
        int j = i - 81920;
        *(u16x4*)(vwb + j * 4) = cast4(*(const f32x4*)(vw + j * 4));
    } else {
        int j = i - 131072;                        // 0..245759
        int e = j * 4;
        int row = e / CTXn;                        // b*80 + l
        int d = e - row * CTXn;
        int b = row / LPn, l = row - b * LPn;
        u16x4 pk;
        if (l < Ln) {
            pk = cast4(*(const f32x4*)(ctx + ((size_t)(b * Ln + l)) * CTXn + d));
        } else {
            pk[0] = 0; pk[1] = 0; pk[2] = 0; pk[3] = 0;
        }
        *(u16x4*)(ctxb + e) = pk;
    }
}

// ---------------- 2: k/v projections via MFMA (kt stored chunked) ----------------
__launch_bounds__(256)
__global__ void k_kv(const u16* __restrict__ kwb, const u16* __restrict__ vwb,
                     const u16* __restrict__ ctxb, u16* __restrict__ kt,
                     u16* __restrict__ v) {
    int b = blockIdx.y;
    int tid = threadIdx.x;
    int wave = tid >> 6, lane = tid & 63;
    int l15 = lane & 15, q4 = lane >> 4;
    int c0 = blockIdx.x * 64 + wave * 16;
    const u16* cb = ctxb + (size_t)b * LPn * CTXn;

    f32x4 ak[5], av[5];
#pragma unroll
    for (int lt = 0; lt < 5; ++lt) {
        ak[lt] = (f32x4){0.f, 0.f, 0.f, 0.f};
        av[lt] = (f32x4){0.f, 0.f, 0.f, 0.f};
    }
    for (int ks = 0; ks < CTXn / 32; ++ks) {
        int kk = ks * 32 + 8 * q4;
        frag8 fk = *(const frag8*)(kwb + (size_t)(c0 + l15) * CTXn + kk);
        frag8 fv = *(const frag8*)(vwb + (size_t)(c0 + l15) * CTXn + kk);
#pragma unroll
        for (int lt = 0; lt < 5; ++lt) {
            frag8 fc = *(const frag8*)(cb + (size_t)(lt * 16 + l15) * CTXn + kk);
            ak[lt] = __builtin_amdgcn_mfma_f32_16x16x32_bf16(fk, fc, ak[lt], 0, 0, 0);
            av[lt] = __builtin_amdgcn_mfma_f32_16x16x32_bf16(fc, fv, av[lt], 0, 0, 0);
        }
    }
    // kt chunked: D row = c (q4*4..+3), col = l (l15)
    int cc0 = c0 + q4 * 4;
    u16* ktb = kt + (size_t)b * 20480;
#pragma unroll
    for (int lt = 0; lt < 5; ++lt) {
        *(u16x4*)(ktb + (size_t)((cc0 >> 3) * LPn + lt * 16 + l15) * 8 + (cc0 & 7)) = cast4(ak[lt]);
        // v: D row = l (q4*4..+3), col = c (l15)
        *(u16x4*)(v + ((size_t)(b * Cn + c0 + l15)) * LKn + lt * 16 + q4 * 4) = cast4(av[lt]);
    }
    u16x4 z; z[0] = 0; z[1] = 0; z[2] = 0; z[3] = 0;
    *(u16x4*)(v + ((size_t)(b * Cn + c0 + l15)) * LKn + 80 + q4 * 4) = z;
}

// ---------------- 3: FUSED q-proj -> QK^T -> softmax -> PV -> out-proj + GN ----------------
// One 64n tile per block. 4 waves. LDS: sX (x bf16, 32KB) + sQH (f32 stage / q / h, 32KB)
// + wl (13KB) = 77KB -> 2 blocks/CU. Weights/kt/v read from global (L2-hot).
__launch_bounds__(256, 2)
__global__ void k_fused(const u16* __restrict__ qwb, const u16* __restrict__ owb,
                        const float* __restrict__ x, const float* __restrict__ qb,
                        const float* __restrict__ obias,
                        const u16* __restrict__ ktg, const u16* __restrict__ vg,
                        u16* __restrict__ t, float* __restrict__ gsum,
                        float* __restrict__ gsq) {
    int nt = blockIdx.x, b = blockIdx.y;
    int tid = threadIdx.x;
    int w = tid >> 6, lane = tid & 63;
    int l15 = lane & 15, q4 = lane >> 4;

    __shared__ __align__(16) u16 sX[16384];     // x tile, bf16 chunked (residual too)
    __shared__ __align__(16) u16 sQH[16384];    // f32 staging, then q tile, then h tile
    __shared__ u16 wl[4][16][104];              // per-wave softmax weights

    // ---- phase 0: x (256c x 64n f32) -> sX bf16 chunked, via padded f32 transpose ----
    // 4 quarters of 64c. sF[64][66] f32 aliases sQH. All LDS ops vectorized/conflict-free.
    {
        float* sF = (float*)sQH;
        const float* xb = x + (size_t)b * Cn * Nn + nt * 64;
        int cs = tid >> 4;              // 0..15
        int ns = (tid & 15) * 4;
        f32x4 xr[4];
#pragma unroll
        for (int i = 0; i < 4; ++i)
            xr[i] = *(const f32x4*)(xb + (size_t)(cs + i * 16) * Nn + ns);
#pragma unroll
        for (int q = 0; q < 4; ++q) {
#pragma unroll
            for (int i = 0; i < 4; ++i)
                *(f32x4*)&sF[(cs + i * 16) * 66 + ns] = xr[i];
            __syncthreads();
            if (q < 3) {
#pragma unroll
                for (int i = 0; i < 4; ++i)
                    xr[i] = *(const f32x4*)(xb + (size_t)((q + 1) * 64 + cs + i * 16) * Nn + ns);
            }
            // transpose: 512 chunks, 2 per lane; reads hit consecutive banks
#pragma unroll
            for (int half = 0; half < 2; ++half) {
                int ci = half * 256 + tid;
                int kcl = ci >> 6, row = ci & 63;
                u16x8 pk;
#pragma unroll
                for (int j = 0; j < 8; ++j) pk[j] = f2b(sF[(kcl * 8 + j) * 66 + row]);
                *(u16x8*)&sX[(size_t)((q * 8 + kcl) * 64 + row) * 8] = pk;
            }
            __syncthreads();
        }
    }

    // ---- phase A: q-GEMM (wave w owns o in [w*64, w*64+64)) ----
    {
        f32x4 acc[4][4];
#pragma unroll
        for (int i = 0; i < 4; ++i)
#pragma unroll
            for (int j = 0; j < 4; ++j) acc[i][j] = (f32x4){0.f, 0.f, 0.f, 0.f};
#pragma unroll
        for (int ks = 0; ks < 8; ++ks) {
            frag8 bf[4];
#pragma unroll
            for (int n4 = 0; n4 < 4; ++n4)
                bf[n4] = *(const frag8*)&sX[(size_t)((ks * 4 + q4) * 64 + n4 * 16 + l15) * 8];
#pragma unroll
            for (int mt = 0; mt < 4; ++mt) {
                frag8 a = *(const frag8*)(qwb + (size_t)((ks * 4 + q4) * 256 + w * 64 + mt * 16 + l15) * 8);
#pragma unroll
                for (int n4 = 0; n4 < 4; ++n4)
                    acc[mt][n4] = __builtin_amdgcn_mfma_f32_16x16x32_bf16(a, bf[n4], acc[mt][n4], 0, 0, 0);
            }
        }
        __syncthreads();    // sF (aliasing sQH) fully consumed; safe to write q
        // D row = o (q4*4+r), col = n (l15): + bias, write sQH chunked
#pragma unroll
        for (int mt = 0; mt < 4; ++mt) {
            int o4 = w * 64 + mt * 16 + q4 * 4;
            f32x4 qb4 = *(const f32x4*)(qb + o4);
#pragma unroll
            for (int n4 = 0; n4 < 4; ++n4) {
                int row = n4 * 16 + l15;
                u16x4 pk;
#pragma unroll
                for (int r = 0; r < 4; ++r) pk[r] = f2b(acc[mt][n4][r] + qb4[r]);
                *(u16x4*)&sQH[(size_t)((o4 >> 3) * 64 + row) * 8 + (o4 & 7)] = pk;
            }
        }
    }
    __syncthreads();

    // ---- phase B: QK^T (wave w owns n-rows [w*16, w*16+16)) + softmax ----
    int rw = w * 16;
    const u16* ktb = ktg + (size_t)b * 20480;
    f32x4 s5[5];
#pragma unroll
    for (int mt = 0; mt < 5; ++mt) s5[mt] = (f32x4){0.f, 0.f, 0.f, 0.f};
#pragma unroll
    for (int ks = 0; ks < 8; ++ks) {
        frag8 bq = *(const frag8*)&sQH[(size_t)((ks * 4 + q4) * 64 + rw + l15) * 8];
#pragma unroll
        for (int mt = 0; mt < 5; ++mt) {
            frag8 ak = *(const frag8*)(ktb + (size_t)((ks * 4 + q4) * 80 + mt * 16 + l15) * 8);
            s5[mt] = __builtin_amdgcn_mfma_f32_16x16x32_bf16(ak, bq, s5[mt], 0, 0, 0);
        }
    }
    // lane: n = l15, l = mt*16 + q4*4 + r
    {
        float m = -3e38f;
#pragma unroll
        for (int mt = 0; mt < 5; ++mt)
#pragma unroll
            for (int r = 0; r < 4; ++r) {
                int l = mt * 16 + q4 * 4 + r;
                if (l < Ln) m = fmaxf(m, s5[mt][r]);
            }
        m = fmaxf(m, __shfl_xor(m, 16));
        m = fmaxf(m, __shfl_xor(m, 32));
        float p[5][4];
        float sum = 0.f;
#pragma unroll
        for (int mt = 0; mt < 5; ++mt)
#pragma unroll
            for (int r = 0; r < 4; ++r) {
                int l = mt * 16 + q4 * 4 + r;
                float e = (l < Ln) ? __expf(s5[mt][r] - m) : 0.f;
                p[mt][r] = e;
                sum += e;
            }
        sum += __shfl_xor(sum, 16);
        sum += __shfl_xor(sum, 32);
        float inv = 1.f / sum;

        u32* wz = (u32*)&wl[w][0][0];           // 832 u32, per-wave region
#pragma unroll
        for (int i = 0; i < 13; ++i) wz[lane + i * 64] = 0;
#pragma unroll
        for (int mt = 0; mt < 5; ++mt)
#pragma unroll
            for (int r = 0; r < 4; ++r) {
                int l = mt * 16 + q4 * 4 + r;
                if (l < Ln) wl[w][l15][l] = f2b(p[mt][r] * inv);
            }
    }
    __syncthreads();    // all sQH(q) reads done -> safe to overwrite with h

    // ---- phase C: PV, swapped operands (D row = c -> u16x4 chunked writes) ----
    {
        frag8 fw[3];
#pragma unroll
        for (int ks = 0; ks < 3; ++ks)
            fw[ks] = *(const frag8*)(&wl[w][l15][ks * 32 + 8 * q4]);
        const u16* vb = vg + (size_t)b * Cn * LKn;
#pragma unroll
        for (int ct = 0; ct < 16; ++ct) {
            f32x4 h = (f32x4){0.f, 0.f, 0.f, 0.f};
#pragma unroll
            for (int ks = 0; ks < 3; ++ks) {
                frag8 fv = *(const frag8*)(vb + (size_t)(ct * 16 + l15) * LKn + ks * 32 + 8 * q4);
                h = __builtin_amdgcn_mfma_f32_16x16x32_bf16(fv, fw[ks], h, 0, 0, 0);
            }
            // c = ct*16 + q4*4 + r (4 consecutive), n = rw + l15
            *(u16x4*)&sQH[(size_t)((ct * 2 + (q4 >> 1)) * 64 + rw + l15) * 8 + (q4 & 1) * 4] = cast4(h);
        }
    }
    __syncthreads();

    // ---- phase D: out-GEMM + bias + residual(sX) + chunked t store + GN partials ----
    {
        f32x4 acc[4][4];
#pragma unroll
        for (int i = 0; i < 4; ++i)
#pragma unroll
            for (int j = 0; j < 4; ++j) acc[i][j] = (f32x4){0.f, 0.f, 0.f, 0.f};
#pragma unroll
        for (int ks = 0; ks < 8; ++ks) {
            frag8 bf[4];
#pragma unroll
            for (int n4 = 0; n4 < 4; ++n4)
                bf[n4] = *(const frag8*)&sQH[(size_t)((ks * 4 + q4) * 64 + n4 * 16 + l15) * 8];
#pragma unroll
            for (int mt = 0; mt < 4; ++mt) {
                frag8 a = *(const frag8*)(owb + (size_t)((ks * 4 + q4) * 256 + w * 64 + mt * 16 + l15) * 8);
#pragma unroll
                for (int n4 = 0; n4 < 4; ++n4)
                    acc[mt][n4] = __builtin_amdgcn_mfma_f32_16x16x32_bf16(a, bf[n4], acc[mt][n4], 0, 0, 0);
            }
        }
        u16* tb = t + ((size_t)(b * 64 + nt)) * 16384;
        float gps[4] = {0.f, 0.f, 0.f, 0.f}, gpq[4] = {0.f, 0.f, 0.f, 0.f};
#pragma unroll
        for (int mt = 0; mt < 4; ++mt) {
            int o4 = w * 64 + mt * 16 + q4 * 4;
            f32x4 ob4 = *(const f32x4*)(obias + o4);
            size_t kcb = (size_t)(o4 >> 3) * 64;
            int off = o4 & 7;
#pragma unroll
            for (int n4 = 0; n4 < 4; ++n4) {
                int row = n4 * 16 + l15;
                size_t idx = (kcb + row) * 8 + off;
                u16x4 xv = *(const u16x4*)&sX[idx];
                u16x4 pk;
#pragma unroll
                for (int r = 0; r < 4; ++r) {
                    float val = acc[mt][n4][r] + ob4[r] + b2f(xv[r]);
                    pk[r] = f2b(val);
                    gps[mt] += val; gpq[mt] += val * val;
                }
                *(u16x4*)(tb + idx) = pk;
            }
        }
        // GN reduce: lane's 4 vals in group g = w*8 + mt*2 + (q4>>1)
#pragma unroll
        for (int mt = 0; mt < 4; ++mt) {
            float s = gps[mt], q = gpq[mt];
            s += __shfl_xor(s, 1);  q += __shfl_xor(q, 1);
            s += __shfl_xor(s, 2);  q += __shfl_xor(q, 2);
            s += __shfl_xor(s, 4);  q += __shfl_xor(q, 4);
            s += __shfl_xor(s, 8);  q += __shfl_xor(q, 8);
            s += __shfl_xor(s, 16); q += __shfl_xor(q, 16);
            if ((lane & 31) == 0) {   // lane 0 (q4 0/1) or lane 32 (q4 2/3)
                int g = w * 8 + mt * 2 + (lane >> 5);
                atomicAdd(&gsum[b * Gn + g], s);
                atomicAdd(&gsq[b * Gn + g], q);
            }
        }
    }
}

// ---------------- 4: GroupNorm apply + Swish (chunked t -> [b][c][n] f32 out) ----------------
__launch_bounds__(256)
__global__ void k_gnapply(const u16* __restrict__ t, const float* __restrict__ gsum,
                          const float* __restrict__ gsq, const float* __restrict__ gamma,
                          const float* __restrict__ beta, float* __restrict__ out) {
    int nt = blockIdx.x, b = blockIdx.y;
    __shared__ __align__(16) u16 s[16384];          // 32KB tile
    const u16* tb = t + ((size_t)(b * 64 + nt)) * 16384;
    int tid = threadIdx.x;
#pragma unroll
    for (int j = 0; j < 8; ++j) {
        int c = j * 256 + tid;
        gl16(tb + (size_t)c * 8, &s[(size_t)c * 8]);
    }
    int c8 = tid >> 3, n8 = tid & 7;                // group g = c8, n-base = n8*8
    float mean = gsum[b * Gn + c8] * (1.0f / 32768.f);
    float var = gsq[b * Gn + c8] * (1.0f / 32768.f) - mean * mean;
    float rstd = rsqrtf(var + 1e-5f);
    __syncthreads();
    u16x8 v[8];
#pragma unroll
    for (int j = 0; j < 8; ++j)
        v[j] = *(const u16x8*)&s[(size_t)(c8 * 64 + n8 * 8 + j) * 8];
    float* ob = out + ((size_t)(b * Cn + c8 * 8)) * Nn + nt * 64 + n8 * 8;
#pragma unroll
    for (int cc = 0; cc < 8; ++cc) {
        float ga = gamma[c8 * 8 + cc], be = beta[c8 * 8 + cc];
        f32x4 lo, hi;
#pragma unroll
        for (int j = 0; j < 4; ++j) {
            float hv = (b2f(v[j][cc]) - mean) * rstd * ga + be;
            lo[j] = hv / (1.f + __expf(-hv));
        }
#pragma unroll
        for (int j = 0; j < 4; ++j) {
            float hv = (b2f(v[j + 4][cc]) - mean) * rstd * ga + be;
            hi[j] = hv / (1.f + __expf(-hv));
        }
        *(f32x4*)(ob + (size_t)cc * Nn) = lo;
        *(f32x4*)(ob + (size_t)cc * Nn + 4) = hi;
    }
}

// ---------------- launcher ----------------
extern "C" void kernel_launch(void* const* d_in, const int* in_sizes, int n_in,
                              void* d_out, int out_size, void* d_ws, size_t ws_size,
                              hipStream_t stream) {
    (void)in_sizes; (void)n_in; (void)out_size; (void)ws_size;
    const float* x     = (const float*)d_in[0];
    const float* ctx   = (const float*)d_in[1];
    const float* qw    = (const float*)d_in[2];
    const float* qb    = (const float*)d_in[3];
    const float* kw    = (const float*)d_in[4];
    const float* vw    = (const float*)d_in[5];
    const float* ow    = (const float*)d_in[6];
    const float* ob    = (const float*)d_in[7];
    const float* gamma = (const float*)d_in[8];
    const float* beta  = (const float*)d_in[9];
    float* out = (float*)d_out;
    char* ws = (char*)d_ws;

    u16* t    = (u16*)(ws + OFF_T);
    u16* ctxb = (u16*)(ws + OFF_CTXB);
    u16* kwb  = (u16*)(ws + OFF_KWB);
    u16* vwb  = (u16*)(ws + OFF_VWB);
    u16* kt   = (u16*)(ws + OFF_KT);
    u16* v    = (u16*)(ws + OFF_V);
    u16* qwb  = (u16*)(ws + OFF_QWB);
    u16* owb  = (u16*)(ws + OFF_OWB);
    float* gsum = (float*)(ws + OFF_GS);
    float* gsq  = (float*)(ws + OFF_GQ);

    k_prep<<<1472, 256, 0, stream>>>(qw, ow, kw, vw, ctx, qwb, owb, kwb, vwb, ctxb, gsum);
    k_kv<<<dim3(4, Bn), 256, 0, stream>>>(kwb, vwb, ctxb, kt, v);
    k_fused<<<dim3(64, Bn), 256, 0, stream>>>(qwb, owb, x, qb, ob, kt, v, t, gsum, gsq);
    k_gnapply<<<dim3(64, Bn), 256, 0, stream>>>(t, gsum, gsq, gamma, beta, out);
}

// Round 10
// 130.099 us; speedup vs baseline: 1.0530x; 1.0444x over previous
//
#include <hip/hip_runtime.h>
#include <cstdint>
#include <cstddef>

// ---------------- problem constants ----------------
#define Bn   16
#define Cn   256
#define Nn   4096      // 16^3 spatial
#define Ln   77
#define LPn  80        // padded L rows (scores), 5 tiles of 16
#define LKn  96        // padded L for PV K-dim (3 k-steps of 32)
#define CTXn 768
#define Gn   32

typedef unsigned short u16;
typedef unsigned int   u32;
using frag8 = __attribute__((ext_vector_type(8))) short;   // 8 x bf16 (4 VGPR)
using f32x4 = __attribute__((ext_vector_type(4))) float;
using u16x4 = __attribute__((ext_vector_type(4))) u16;
using u16x8 = __attribute__((ext_vector_type(8))) u16;

__device__ __forceinline__ float b2f(u16 b) {
    union { u32 u; float f; } v; v.u = ((u32)b) << 16; return v.f;
}
__device__ __forceinline__ u16 f2b(float f) {  // RNE f32->bf16
    union { float f; u32 u; } v; v.f = f;
    u32 u = v.u;
    return (u16)((u + 0x7fffu + ((u >> 16) & 1u)) >> 16);
}
__device__ __forceinline__ u16x4 cast4(f32x4 s) {
    u16x4 p; p[0] = f2b(s[0]); p[1] = f2b(s[1]); p[2] = f2b(s[2]); p[3] = f2b(s[3]);
    return p;
}
// async global->LDS, 16B per lane. LDS dest must be lane-linear (base + lane*16).
__device__ __forceinline__ void gl16(const u16* g, u16* l) {
    __builtin_amdgcn_global_load_lds((const __attribute__((address_space(1))) u32*)g,
                                     (__attribute__((address_space(3))) u32*)l, 16, 0, 0);
}

// Chunked activation layout (per 64n tile): [kc(32)][row(64)] of 16B chunks (8 ch).
//   u16 index = (kc*64 + row)*8 + (c&7),  kc = c>>3, row = n&63.
// Chunked weight layout: [kc(32)][row(256)]: u16 idx = ((k>>3)*256 + r)*8 + (k&7).
// Chunked kt layout:     [b][kc(32)][l(80)]: u16 idx = b*20480 + ((c>>3)*80 + l)*8 + (c&7).

// ---------------- ws layout (bytes) ----------------
static const size_t OFF_T   = 33554432;             // bf16 chunked t [B][64][2048][8]
static const size_t OFF_CTXB = 33554432 - 2097152;  // bf16 [16][80][768] (dead before fused)
static const size_t OFF_KWB  = 35520512;            // bf16 [256][768] (dead after k_kv)
static const size_t OFF_VWB  = 35913728;            // bf16 [256][768] (dead after k_kv)
static const size_t OFF_KT  = 67108864;             // bf16 chunked [B][32][80][8] (40KB/b)
static const size_t OFF_V   = 67764224;             // bf16 [B][256][96]
static const size_t OFF_QWB = 68550656;             // bf16 chunked [32][256][8]
static const size_t OFF_OWB = 68681728;             // bf16 chunked [32][256][8]
static const size_t OFF_GS  = 68812800;             // f32 [B][32]
static const size_t OFF_GQ  = 68814848;             // f32 [B][32]
// kwb/vwb overlap t's region but die before k_fused writes t (stream-serialized).

// ---------------- 1: cast to bf16 (qw/ow chunked) + zero GN accumulators ----------------
__global__ void k_prep(const float* __restrict__ qw, const float* __restrict__ ow,
                       const float* __restrict__ kw, const float* __restrict__ vw,
                       const float* __restrict__ ctx,
                       u16* __restrict__ qwb, u16* __restrict__ owb,
                       u16* __restrict__ kwb, u16* __restrict__ vwb,
                       u16* __restrict__ ctxb, float* __restrict__ gz) {
    int i = blockIdx.x * 256 + threadIdx.x;        // 376832 total
    if (i < 1024) gz[i] = 0.f;                     // gsum+gsq (4KB, contiguous)
    if (i < 16384) {
        int e = i * 4; int r = e >> 8; int k = e & 255;
        *(u16x4*)(qwb + ((size_t)((k >> 3) * 256 + r) * 8 + (k & 7))) =
            cast4(*(const f32x4*)(qw + e));
    } else if (i < 32768) {
        int e = (i - 16384) * 4; int r = e >> 8; int k = e & 255;
        *(u16x4*)(owb + ((size_t)((k >> 3) * 256 + r) * 8 + (k & 7))) =
            cast4(*(const f32x4*)(ow + e));
    } else if (i < 81920) {
        int j = i - 32768;
        *(u16x4*)(kwb + j * 4) = cast4(*(const f32x4*)(kw + j * 4));
    } else if (i < 131072) {
        int j = i - 81920;
        *(u16x4*)(vwb + j * 4) = cast4(*(const f32x4*)(vw + j * 4));
    } else {
        int j = i - 131072;                        // 0..245759
        int e = j * 4;
        int row = e / CTXn;                        // b*80 + l
        int d = e - row * CTXn;
        int b = row / LPn, l = row - b * LPn;
        u16x4 pk;
        if (l < Ln) {
            pk = cast4(*(const f32x4*)(ctx + ((size_t)(b * Ln + l)) * CTXn + d));
        } else {
            pk[0] = 0; pk[1] = 0; pk[2] = 0; pk[3] = 0;
        }
        *(u16x4*)(ctxb + e) = pk;
    }
}

// ---------------- 2: k/v projections via MFMA (kt stored chunked) ----------------
__launch_bounds__(256)
__global__ void k_kv(const u16* __restrict__ kwb, const u16* __restrict__ vwb,
                     const u16* __restrict__ ctxb, u16* __restrict__ kt,
                     u16* __restrict__ v) {
    int b = blockIdx.y;
    int tid = threadIdx.x;
    int wave = tid >> 6, lane = tid & 63;
    int l15 = lane & 15, q4 = lane >> 4;
    int c0 = blockIdx.x * 64 + wave * 16;
    const u16* cb = ctxb + (size_t)b * LPn * CTXn;

    f32x4 ak[5], av[5];
#pragma unroll
    for (int lt = 0; lt < 5; ++lt) {
        ak[lt] = (f32x4){0.f, 0.f, 0.f, 0.f};
        av[lt] = (f32x4){0.f, 0.f, 0.f, 0.f};
    }
    for (int ks = 0; ks < CTXn / 32; ++ks) {
        int kk = ks * 32 + 8 * q4;
        frag8 fk = *(const frag8*)(kwb + (size_t)(c0 + l15) * CTXn + kk);
        frag8 fv = *(const frag8*)(vwb + (size_t)(c0 + l15) * CTXn + kk);
#pragma unroll
        for (int lt = 0; lt < 5; ++lt) {
            frag8 fc = *(const frag8*)(cb + (size_t)(lt * 16 + l15) * CTXn + kk);
            ak[lt] = __builtin_amdgcn_mfma_f32_16x16x32_bf16(fk, fc, ak[lt], 0, 0, 0);
            av[lt] = __builtin_amdgcn_mfma_f32_16x16x32_bf16(fc, fv, av[lt], 0, 0, 0);
        }
    }
    // kt chunked: D row = c (q4*4..+3), col = l (l15)
    int cc0 = c0 + q4 * 4;
    u16* ktb = kt + (size_t)b * 20480;
#pragma unroll
    for (int lt = 0; lt < 5; ++lt) {
        *(u16x4*)(ktb + (size_t)((cc0 >> 3) * LPn + lt * 16 + l15) * 8 + (cc0 & 7)) = cast4(ak[lt]);
        // v: D row = l (q4*4..+3), col = c (l15)
        *(u16x4*)(v + ((size_t)(b * Cn + c0 + l15)) * LKn + lt * 16 + q4 * 4) = cast4(av[lt]);
    }
    u16x4 z; z[0] = 0; z[1] = 0; z[2] = 0; z[3] = 0;
    *(u16x4*)(v + ((size_t)(b * Cn + c0 + l15)) * LKn + 80 + q4 * 4) = z;
}

// ---------------- 3: FUSED q-proj -> QK^T -> softmax -> PV -> out-proj + GN ----------------
// One 64n tile per block. 4 waves, 4 barriers. All global operands prefetched into
// register bursts one phase ahead (phase-level async). LDS 77KB -> 2 blocks/CU.
__launch_bounds__(256, 2)
__global__ void k_fused(const u16* __restrict__ qwb, const u16* __restrict__ owb,
                        const float* __restrict__ x, const float* __restrict__ qb,
                        const float* __restrict__ obias,
                        const u16* __restrict__ ktg, const u16* __restrict__ vg,
                        u16* __restrict__ t, float* __restrict__ gsum,
                        float* __restrict__ gsq) {
    int nt = blockIdx.x, b = blockIdx.y;
    int tid = threadIdx.x;
    int w = tid >> 6, lane = tid & 63;
    int l15 = lane & 15, q4 = lane >> 4;

    __shared__ __align__(16) u16 sX[16384];     // x tile, bf16 chunked (residual too)
    __shared__ __align__(16) u16 sQH[16384];    // per-wave f32 scratch, then q, then h
    __shared__ u16 wl[4][16][104];              // per-wave softmax weights

    // ---- phase 0: wave-local transpose of this wave's 64c quarter ----
    // wave w: c in [w*64, w*64+64), all 64 n. Private f32 scratch [16][66] in sQH.
    {
        float* sF = (float*)&sQH[w * 2176];     // 4224B used, 4352B stride, 4 waves < 32KB
        const float* xb = x + (size_t)b * Cn * Nn + nt * 64;
        int rS = lane >> 2;                     // 0..15
        int cS = (lane & 3) * 16;               // col base (16 f32 per lane, contiguous)

        f32x4 xr[4];
#pragma unroll
        for (int j = 0; j < 4; ++j)
            xr[j] = *(const f32x4*)(xb + (size_t)(w * 64 + rS) * Nn + cS + j * 4);

        // prefetch ALL qw frags now; they land during the transpose
        frag8 aq[4][8];
#pragma unroll
        for (int mt = 0; mt < 4; ++mt)
#pragma unroll
            for (int ks = 0; ks < 8; ++ks)
                aq[mt][ks] = *(const frag8*)(qwb + (size_t)((ks * 4 + q4) * 256 + w * 64 + mt * 16 + l15) * 8);

#pragma unroll
        for (int s = 0; s < 4; ++s) {
#pragma unroll
            for (int j = 0; j < 4; ++j)
                *(f32x4*)&sF[rS * 66 + cS + j * 4] = xr[j];
            if (s < 3) {
#pragma unroll
                for (int j = 0; j < 4; ++j)
                    xr[j] = *(const f32x4*)(xb + (size_t)(w * 64 + (s + 1) * 16 + rS) * Nn + cS + j * 4);
            }
            // wave-local RAW on sF: compiler inserts lgkmcnt; no barrier needed
#pragma unroll
            for (int k = 0; k < 2; ++k) {
                u16x8 pk;
#pragma unroll
                for (int jj = 0; jj < 8; ++jj) pk[jj] = f2b(sF[(k * 8 + jj) * 66 + lane]);
                int kc = w * 8 + s * 2 + k;
                *(u16x8*)&sX[(size_t)(kc * 64 + lane) * 8] = pk;
            }
        }
        __syncthreads();    // barrier 1: sX complete, sF scratch dead

        // ---- phase A: q-GEMM (weights already in regs) ----
        f32x4 acc[4][4];
#pragma unroll
        for (int i = 0; i < 4; ++i)
#pragma unroll
            for (int j = 0; j < 4; ++j) acc[i][j] = (f32x4){0.f, 0.f, 0.f, 0.f};
#pragma unroll
        for (int ks = 0; ks < 8; ++ks) {
            frag8 bf[4];
#pragma unroll
            for (int n4 = 0; n4 < 4; ++n4)
                bf[n4] = *(const frag8*)&sX[(size_t)((ks * 4 + q4) * 64 + n4 * 16 + l15) * 8];
#pragma unroll
            for (int mt = 0; mt < 4; ++mt)
#pragma unroll
                for (int n4 = 0; n4 < 4; ++n4)
                    acc[mt][n4] = __builtin_amdgcn_mfma_f32_16x16x32_bf16(aq[mt][ks], bf[n4], acc[mt][n4], 0, 0, 0);
        }

        // prefetch kt first half (ks 0..3); lands under the q epilogue + barrier
        const u16* ktb = ktg + (size_t)b * 20480;
        frag8 ktf[8][5];
#pragma unroll
        for (int ks = 0; ks < 4; ++ks)
#pragma unroll
            for (int mt = 0; mt < 5; ++mt)
                ktf[ks][mt] = *(const frag8*)(ktb + (size_t)((ks * 4 + q4) * 80 + mt * 16 + l15) * 8);

        // q epilogue: D row = o (q4*4+r), col = n (l15) -> sQH chunked
#pragma unroll
        for (int mt = 0; mt < 4; ++mt) {
            int o4 = w * 64 + mt * 16 + q4 * 4;
            f32x4 qb4 = *(const f32x4*)(qb + o4);
#pragma unroll
            for (int n4 = 0; n4 < 4; ++n4) {
                int row = n4 * 16 + l15;
                u16x4 pk;
#pragma unroll
                for (int r = 0; r < 4; ++r) pk[r] = f2b(acc[mt][n4][r] + qb4[r]);
                *(u16x4*)&sQH[(size_t)((o4 >> 3) * 64 + row) * 8 + (o4 & 7)] = pk;
            }
        }
        __syncthreads();    // barrier 2: q complete

        // ---- phase B: QK^T + softmax (wave w owns n-rows [w*16, w*16+16)) ----
        int rw = w * 16;
        // kt second half; lands under the first-half MFMAs
#pragma unroll
        for (int ks = 4; ks < 8; ++ks)
#pragma unroll
            for (int mt = 0; mt < 5; ++mt)
                ktf[ks][mt] = *(const frag8*)(ktb + (size_t)((ks * 4 + q4) * 80 + mt * 16 + l15) * 8);

        f32x4 s5[5];
#pragma unroll
        for (int mt = 0; mt < 5; ++mt) s5[mt] = (f32x4){0.f, 0.f, 0.f, 0.f};
#pragma unroll
        for (int ks = 0; ks < 8; ++ks) {
            frag8 bq = *(const frag8*)&sQH[(size_t)((ks * 4 + q4) * 64 + rw + l15) * 8];
#pragma unroll
            for (int mt = 0; mt < 5; ++mt)
                s5[mt] = __builtin_amdgcn_mfma_f32_16x16x32_bf16(ktf[ks][mt], bq, s5[mt], 0, 0, 0);
        }

        // prefetch v first half (ct 0..7); lands under softmax VALU
        const u16* vb = vg + (size_t)b * Cn * LKn;
        frag8 vf[16][3];
#pragma unroll
        for (int ct = 0; ct < 8; ++ct)
#pragma unroll
            for (int ks = 0; ks < 3; ++ks)
                vf[ct][ks] = *(const frag8*)(vb + (size_t)(ct * 16 + l15) * LKn + ks * 32 + 8 * q4);

        // softmax: lane n = l15, l = mt*16 + q4*4 + r
        {
            float m = -3e38f;
#pragma unroll
            for (int mt = 0; mt < 5; ++mt)
#pragma unroll
                for (int r = 0; r < 4; ++r) {
                    int l = mt * 16 + q4 * 4 + r;
                    if (l < Ln) m = fmaxf(m, s5[mt][r]);
                }
            m = fmaxf(m, __shfl_xor(m, 16));
            m = fmaxf(m, __shfl_xor(m, 32));
            float p[5][4];
            float sum = 0.f;
#pragma unroll
            for (int mt = 0; mt < 5; ++mt)
#pragma unroll
                for (int r = 0; r < 4; ++r) {
                    int l = mt * 16 + q4 * 4 + r;
                    float e = (l < Ln) ? __expf(s5[mt][r] - m) : 0.f;
                    p[mt][r] = e;
                    sum += e;
                }
            sum += __shfl_xor(sum, 16);
            sum += __shfl_xor(sum, 32);
            float inv = 1.f / sum;

            u32* wz = (u32*)&wl[w][0][0];       // 832 u32, per-wave region
#pragma unroll
            for (int i = 0; i < 13; ++i) wz[lane + i * 64] = 0;
#pragma unroll
            for (int mt = 0; mt < 5; ++mt)
#pragma unroll
                for (int r = 0; r < 4; ++r) {
                    int l = mt * 16 + q4 * 4 + r;
                    if (l < Ln) wl[w][l15][l] = f2b(p[mt][r] * inv);
                }
        }
        __syncthreads();    // barrier 3: all q reads done -> sQH reusable for h

        // ---- phase C: PV, swapped operands (D row = c -> u16x4 chunked writes) ----
        frag8 fw[3];
#pragma unroll
        for (int ks = 0; ks < 3; ++ks)
            fw[ks] = *(const frag8*)(&wl[w][l15][ks * 32 + 8 * q4]);
        // v second half; lands under the first-half MFMAs
#pragma unroll
        for (int ct = 8; ct < 16; ++ct)
#pragma unroll
            for (int ks = 0; ks < 3; ++ks)
                vf[ct][ks] = *(const frag8*)(vb + (size_t)(ct * 16 + l15) * LKn + ks * 32 + 8 * q4);

#pragma unroll
        for (int ct = 0; ct < 8; ++ct) {
            f32x4 h = (f32x4){0.f, 0.f, 0.f, 0.f};
#pragma unroll
            for (int ks = 0; ks < 3; ++ks)
                h = __builtin_amdgcn_mfma_f32_16x16x32_bf16(vf[ct][ks], fw[ks], h, 0, 0, 0);
            *(u16x4*)&sQH[(size_t)((ct * 2 + (q4 >> 1)) * 64 + rw + l15) * 8 + (q4 & 1) * 4] = cast4(h);
        }
        // prefetch ow first half (mt 0,1); vf first half is dead
        frag8 ao[4][8];
#pragma unroll
        for (int mt = 0; mt < 2; ++mt)
#pragma unroll
            for (int ks = 0; ks < 8; ++ks)
                ao[mt][ks] = *(const frag8*)(owb + (size_t)((ks * 4 + q4) * 256 + w * 64 + mt * 16 + l15) * 8);
#pragma unroll
        for (int ct = 8; ct < 16; ++ct) {
            f32x4 h = (f32x4){0.f, 0.f, 0.f, 0.f};
#pragma unroll
            for (int ks = 0; ks < 3; ++ks)
                h = __builtin_amdgcn_mfma_f32_16x16x32_bf16(vf[ct][ks], fw[ks], h, 0, 0, 0);
            *(u16x4*)&sQH[(size_t)((ct * 2 + (q4 >> 1)) * 64 + rw + l15) * 8 + (q4 & 1) * 4] = cast4(h);
        }
        // ow second half
#pragma unroll
        for (int mt = 2; mt < 4; ++mt)
#pragma unroll
            for (int ks = 0; ks < 8; ++ks)
                ao[mt][ks] = *(const frag8*)(owb + (size_t)((ks * 4 + q4) * 256 + w * 64 + mt * 16 + l15) * 8);
        __syncthreads();    // barrier 4: h complete

        // ---- phase D: out-GEMM + bias + residual(sX) + chunked t store + GN partials ----
        f32x4 dcc[4][4];
#pragma unroll
        for (int i = 0; i < 4; ++i)
#pragma unroll
            for (int j = 0; j < 4; ++j) dcc[i][j] = (f32x4){0.f, 0.f, 0.f, 0.f};
#pragma unroll
        for (int ks = 0; ks < 8; ++ks) {
            frag8 bf[4];
#pragma unroll
            for (int n4 = 0; n4 < 4; ++n4)
                bf[n4] = *(const frag8*)&sQH[(size_t)((ks * 4 + q4) * 64 + n4 * 16 + l15) * 8];
#pragma unroll
            for (int mt = 0; mt < 4; ++mt)
#pragma unroll
                for (int n4 = 0; n4 < 4; ++n4)
                    dcc[mt][n4] = __builtin_amdgcn_mfma_f32_16x16x32_bf16(ao[mt][ks], bf[n4], dcc[mt][n4], 0, 0, 0);
        }
        u16* tb = t + ((size_t)(b * 64 + nt)) * 16384;
        float gps[4] = {0.f, 0.f, 0.f, 0.f}, gpq[4] = {0.f, 0.f, 0.f, 0.f};
#pragma unroll
        for (int mt = 0; mt < 4; ++mt) {
            int o4 = w * 64 + mt * 16 + q4 * 4;
            f32x4 ob4 = *(const f32x4*)(obias + o4);
            size_t kcb = (size_t)(o4 >> 3) * 64;
            int off = o4 & 7;
#pragma unroll
            for (int n4 = 0; n4 < 4; ++n4) {
                int row = n4 * 16 + l15;
                size_t idx = (kcb + row) * 8 + off;
                u16x4 xv = *(const u16x4*)&sX[idx];
                u16x4 pk;
#pragma unroll
                for (int r = 0; r < 4; ++r) {
                    float val = dcc[mt][n4][r] + ob4[r] + b2f(xv[r]);
                    pk[r] = f2b(val);
                    gps[mt] += val; gpq[mt] += val * val;
                }
                *(u16x4*)(tb + idx) = pk;
            }
        }
        // GN reduce: lane's 4 vals in group g = w*8 + mt*2 + (q4>>1)
#pragma unroll
        for (int mt = 0; mt < 4; ++mt) {
            float s = gps[mt], q = gpq[mt];
            s += __shfl_xor(s, 1);  q += __shfl_xor(q, 1);
            s += __shfl_xor(s, 2);  q += __shfl_xor(q, 2);
            s += __shfl_xor(s, 4);  q += __shfl_xor(q, 4);
            s += __shfl_xor(s, 8);  q += __shfl_xor(q, 8);
            s += __shfl_xor(s, 16); q += __shfl_xor(q, 16);
            if ((lane & 31) == 0) {   // lane 0 (q4 0/1) or lane 32 (q4 2/3)
                int g = w * 8 + mt * 2 + (lane >> 5);
                atomicAdd(&gsum[b * Gn + g], s);
                atomicAdd(&gsq[b * Gn + g], q);
            }
        }
    }
}

// ---------------- 4: GroupNorm apply + Swish (chunked t -> [b][c][n] f32 out) ----------------
__launch_bounds__(256)
__global__ void k_gnapply(const u16* __restrict__ t, const float* __restrict__ gsum,
                          const float* __restrict__ gsq, const float* __restrict__ gamma,
                          const float* __restrict__ beta, float* __restrict__ out) {
    int nt = blockIdx.x, b = blockIdx.y;
    __shared__ __align__(16) u16 s[16384];          // 32KB tile
    const u16* tb = t + ((size_t)(b * 64 + nt)) * 16384;
    int tid = threadIdx.x;
#pragma unroll
    for (int j = 0; j < 8; ++j) {
        int c = j * 256 + tid;
        gl16(tb + (size_t)c * 8, &s[(size_t)c * 8]);
    }
    int c8 = tid >> 3, n8 = tid & 7;                // group g = c8, n-base = n8*8
    float mean = gsum[b * Gn + c8] * (1.0f / 32768.f);
    float var = gsq[b * Gn + c8] * (1.0f / 32768.f) - mean * mean;
    float rstd = rsqrtf(var + 1e-5f);
    __syncthreads();
    u16x8 v[8];
#pragma unroll
    for (int j = 0; j < 8; ++j)
        v[j] = *(const u16x8*)&s[(size_t)(c8 * 64 + n8 * 8 + j) * 8];
    float* ob = out + ((size_t)(b * Cn + c8 * 8)) * Nn + nt * 64 + n8 * 8;
#pragma unroll
    for (int cc = 0; cc < 8; ++cc) {
        float ga = gamma[c8 * 8 + cc], be = beta[c8 * 8 + cc];
        f32x4 lo, hi;
#pragma unroll
        for (int j = 0; j < 4; ++j) {
            float hv = (b2f(v[j][cc]) - mean) * rstd * ga + be;
            lo[j] = hv / (1.f + __expf(-hv));
        }
#pragma unroll
        for (int j = 0; j < 4; ++j) {
            float hv = (b2f(v[j + 4][cc]) - mean) * rstd * ga + be;
            hi[j] = hv / (1.f + __expf(-hv));
        }
        *(f32x4*)(ob + (size_t)cc * Nn) = lo;
        *(f32x4*)(ob + (size_t)cc * Nn + 4) = hi;
    }
}

// ---------------- launcher ----------------
extern "C" void kernel_launch(void* const* d_in, const int* in_sizes, int n_in,
                              void* d_out, int out_size, void* d_ws, size_t ws_size,
                              hipStream_t stream) {
    (void)in_sizes; (void)n_in; (void)out_size; (void)ws_size;
    const float* x     = (const float*)d_in[0];
    const float* ctx   = (const float*)d_in[1];
    const float* qw    = (const float*)d_in[2];
    const float* qb    = (const float*)d_in[3];
    const float* kw    = (const float*)d_in[4];
    const float* vw    = (const float*)d_in[5];
    const float* ow    = (const float*)d_in[6];
    const float* ob    = (const float*)d_in[7];
    const float* gamma = (const float*)d_in[8];
    const float* beta  = (const float*)d_in[9];
    float* out = (float*)d_out;
    char* ws = (char*)d_ws;

    u16* t    = (u16*)(ws + OFF_T);
    u16* ctxb = (u16*)(ws + OFF_CTXB);
    u16* kwb  = (u16*)(ws + OFF_KWB);
    u16* vwb  = (u16*)(ws + OFF_VWB);
    u16* kt   = (u16*)(ws + OFF_KT);
    u16* v    = (u16*)(ws + OFF_V);
    u16* qwb  = (u16*)(ws + OFF_QWB);
    u16* owb  = (u16*)(ws + OFF_OWB);
    float* gsum = (float*)(ws + OFF_GS);
    float* gsq  = (float*)(ws + OFF_GQ);

    k_prep<<<1472, 256, 0, stream>>>(qw, ow, kw, vw, ctx, qwb, owb, kwb, vwb, ctxb, gsum);
    k_kv<<<dim3(4, Bn), 256, 0, stream>>>(kwb, vwb, ctxb, kt, v);
    k_fused<<<dim3(64, Bn), 256, 0, stream>>>(qwb, owb, x, qb, ob, kt, v, t, gsum, gsq);
    k_gnapply<<<dim3(64, Bn), 256, 0, stream>>>(t, gsum, gsq, gamma, beta, out);
}